// Round 5
// baseline (6496.603 us; speedup 1.0000x reference)
//
#include <hip/hip_runtime.h>
#include <hip/hip_bf16.h>
#include <math.h>

// Problem dims (fixed)
#define T_STEPS 512
#define IN_DIM  1024
#define H_DIM   2048
#define Y_DIM   1024

// K2 geometry: 256 blocks x 256 threads (4 waves). Wave w owns columns
// j0 = 8*blockIdx + 2w and j0+1. 1024 producer waves, 1 wave per SIMD.
#define NBLK2 256
#define BT2   256

// ---------- helpers ----------
static __device__ __forceinline__ unsigned f2bf(float f) {
    unsigned u = __float_as_uint(f);
    return ((u + 0x7FFFu + ((u >> 16) & 1u)) >> 16) & 0xFFFFu;   // RNE
}
static __device__ __forceinline__ float bflo(unsigned p) { return __uint_as_float(p << 16); }
static __device__ __forceinline__ float bfhi(unsigned p) { return __uint_as_float(p & 0xFFFF0000u); }

// ---------- K1 / K3: tiled fp32 GEMM, C[M,N] = A[M,K] @ B[K,N] + bias[N] ----------
#define TM 64
#define TN 128
#define TK 16

__global__ __launch_bounds__(256) void gemm_bias(
    const float* __restrict__ A, const float* __restrict__ B,
    const float* __restrict__ bias, float* __restrict__ C,
    int M, int N, int K, int lda, int ldb, int ldc)
{
    __shared__ float As[TK][TM + 4];
    __shared__ float Bs[TK][TN + 4];

    const int n0 = blockIdx.x * TN;
    const int m0 = blockIdx.y * TM;
    const int tid = threadIdx.x;
    const int tx = tid & 15;        // N: 8 floats each
    const int ty = tid >> 4;        // M: 4 rows each

    float acc[4][8] = {};

    for (int k0 = 0; k0 < K; k0 += TK) {
        {
            int mm = tid & 63, kq = tid >> 6;
            float4 a = *(const float4*)&A[(m0 + mm) * lda + k0 + 4 * kq];
            As[4 * kq + 0][mm] = a.x;
            As[4 * kq + 1][mm] = a.y;
            As[4 * kq + 2][mm] = a.z;
            As[4 * kq + 3][mm] = a.w;
        }
        #pragma unroll
        for (int l = tid; l < 512; l += 256) {
            int kk = l >> 5, jj = (l & 31) * 4;
            *(float4*)&Bs[kk][jj] = *(const float4*)&B[(k0 + kk) * ldb + n0 + jj];
        }
        __syncthreads();
        #pragma unroll
        for (int kk = 0; kk < TK; ++kk) {
            float4 a  = *(const float4*)&As[kk][ty * 4];
            float4 b0 = *(const float4*)&Bs[kk][tx * 8];
            float4 b1 = *(const float4*)&Bs[kk][tx * 8 + 4];
            const float av[4] = {a.x, a.y, a.z, a.w};
            const float bv[8] = {b0.x, b0.y, b0.z, b0.w, b1.x, b1.y, b1.z, b1.w};
            #pragma unroll
            for (int r = 0; r < 4; ++r)
                #pragma unroll
                for (int c = 0; c < 8; ++c)
                    acc[r][c] = fmaf(av[r], bv[c], acc[r][c]);
        }
        __syncthreads();
    }

    float4 bv0 = *(const float4*)&bias[n0 + tx * 8];
    float4 bv1 = *(const float4*)&bias[n0 + tx * 8 + 4];
    const float bb[8] = {bv0.x, bv0.y, bv0.z, bv0.w, bv1.x, bv1.y, bv1.z, bv1.w};
    #pragma unroll
    for (int r = 0; r < 4; ++r) {
        float4 o0, o1;
        o0.x = acc[r][0] + bb[0]; o0.y = acc[r][1] + bb[1];
        o0.z = acc[r][2] + bb[2]; o0.w = acc[r][3] + bb[3];
        o1.x = acc[r][4] + bb[4]; o1.y = acc[r][5] + bb[5];
        o1.z = acc[r][6] + bb[6]; o1.w = acc[r][7] + bb[7];
        float* cp = &C[(m0 + ty * 4 + r) * ldc + n0 + tx * 8];
        *(float4*)cp = o0;
        *(float4*)(cp + 4) = o1;
    }
}

// ---------- K2: barrier-free tagged-value dataflow recurrence ----------
// Hx[t][j] is an 8B pair (f32 h-value, u32 epoch=t+1) written with ONE relaxed
// agent-scope atomic store: the readiness tag travels atomically with the
// value, so no fences, no RMWs, no barrier, no __syncthreads. Consumers
// batch-issue all 32 tagged loads, then re-load only stale elements.
// Workspace is re-poisoned to 0xAA before every launch, so epoch values
// 1..512 can never false-match stale data (0xAAAAAAAA).
__global__ __launch_bounds__(BT2) void gru_seq(
    const float* __restrict__ Wu_h,   // = Wu + IN_DIM*H_DIM  (h-part rows)
    const float* __restrict__ Wc_h,
    const float* __restrict__ XU,     // [T,H]  x@Wu_x + bu
    const float* __restrict__ XC,     // [T,H]  x@Wc_x + bc
    const float* __restrict__ h0,     // [H]
    unsigned long long* __restrict__ Hx,  // [T,H] tagged pairs
    float* __restrict__ H)                // [T,H] plain f32 (for K3)
{
    const int tid  = threadIdx.x;
    const int w    = tid >> 6;
    const int lane = tid & 63;
    const int j0   = blockIdx.x * 8 + 2 * w;

    // ---- one-time weight staging into registers ----
    // wr[2m+c][q] packs bf16 of W[(2q)*64+lane][j0+c] (lo) and W[(2q+1)*64+lane][j0+c] (hi)
    unsigned wr[4][16];
    #pragma unroll
    for (int m = 0; m < 2; ++m) {
        const float* W = m ? Wc_h : Wu_h;
        #pragma unroll
        for (int c = 0; c < 2; ++c) {
            #pragma unroll
            for (int q = 0; q < 16; ++q) {
                float v0 = W[(size_t)((2 * q) * 64 + lane) * H_DIM + j0 + c];
                float v1 = W[(size_t)((2 * q + 1) * 64 + lane) * H_DIM + j0 + c];
                wr[2 * m + c][q] = f2bf(v0) | (f2bf(v1) << 16);
            }
        }
    }

    // carried h values for this wave's own columns (used by lane 0 only)
    float hc0 = h0[j0], hc1 = h0[j0 + 1];

    for (int t = 0; t < T_STEPS; ++t) {
        // x-contributions (read-only, normal cached loads)
        float2 xu = make_float2(0.f, 0.f), xc = make_float2(0.f, 0.f);
        if (lane == 0) {
            xu = *(const float2*)(XU + (size_t)t * H_DIM + j0);
            xc = *(const float2*)(XC + (size_t)t * H_DIM + j0);
        }

        // ---- acquire h[t-1]: 32 tagged loads, batch-issued, per-element retry ----
        float hv[32];
        if (t == 0) {
            #pragma unroll
            for (int i = 0; i < 32; ++i) hv[i] = h0[i * 64 + lane];
        } else {
            const unsigned long long* src = Hx + (size_t)(t - 1) * H_DIM;
            unsigned long long p[32];
            #pragma unroll
            for (int i = 0; i < 32; ++i)
                p[i] = __hip_atomic_load(src + i * 64 + lane,
                                         __ATOMIC_RELAXED, __HIP_MEMORY_SCOPE_AGENT);
            #pragma unroll
            for (int i = 0; i < 32; ++i) {
                while ((unsigned)(p[i] >> 32) != (unsigned)t) {
                    p[i] = __hip_atomic_load(src + i * 64 + lane,
                                             __ATOMIC_RELAXED, __HIP_MEMORY_SCOPE_AGENT);
                }
            }
            #pragma unroll
            for (int i = 0; i < 32; ++i) hv[i] = __uint_as_float((unsigned)p[i]);
        }

        // ---- 4 dot products (u,c for 2 columns) ----
        float a0 = 0.f, a1 = 0.f, a2 = 0.f, a3 = 0.f;
        #pragma unroll
        for (int i = 0; i < 32; ++i) {
            const int q = i >> 1;
            float hx = hv[i];
            float wu0 = (i & 1) ? bfhi(wr[0][q]) : bflo(wr[0][q]);
            float wu1 = (i & 1) ? bfhi(wr[1][q]) : bflo(wr[1][q]);
            float wc0 = (i & 1) ? bfhi(wr[2][q]) : bflo(wr[2][q]);
            float wc1 = (i & 1) ? bfhi(wr[3][q]) : bflo(wr[3][q]);
            a0 = fmaf(hx, wu0, a0);
            a1 = fmaf(hx, wu1, a1);
            a2 = fmaf(hx, wc0, a2);
            a3 = fmaf(hx, wc1, a3);
        }
        #pragma unroll
        for (int off = 32; off; off >>= 1) {
            a0 += __shfl_down(a0, off);
            a1 += __shfl_down(a1, off);
            a2 += __shfl_down(a2, off);
            a3 += __shfl_down(a3, off);
        }

        if (lane == 0) {
            float u0 = 1.f / (1.f + expf(-(a0 + xu.x)));
            float u1 = 1.f / (1.f + expf(-(a1 + xu.y)));
            float c0 = tanhf(a2 + xc.x);
            float c1 = tanhf(a3 + xc.y);
            float hn0 = u0 * c0 + (1.f - u0) * hc0;
            float hn1 = u1 * c1 + (1.f - u1) * hc1;
            hc0 = hn0; hc1 = hn1;

            unsigned long long ep = ((unsigned long long)(unsigned)(t + 1)) << 32;
            __hip_atomic_store(Hx + (size_t)t * H_DIM + j0,
                               ep | __float_as_uint(hn0),
                               __ATOMIC_RELAXED, __HIP_MEMORY_SCOPE_AGENT);
            __hip_atomic_store(Hx + (size_t)t * H_DIM + j0 + 1,
                               ep | __float_as_uint(hn1),
                               __ATOMIC_RELAXED, __HIP_MEMORY_SCOPE_AGENT);
            // plain copy for K3 (normal cached store; flushed at kernel end)
            *(float2*)(H + (size_t)t * H_DIM + j0) = make_float2(hn0, hn1);
        }
    }
}

extern "C" void kernel_launch(void* const* d_in, const int* in_sizes, int n_in,
                              void* d_out, int out_size, void* d_ws, size_t ws_size,
                              hipStream_t stream)
{
    const float* x   = (const float*)d_in[0];   // [1,512,1024]
    const float* h0  = (const float*)d_in[1];   // [2048]
    const float* Wc  = (const float*)d_in[2];   // [3072,2048]
    const float* Wu  = (const float*)d_in[3];   // [3072,2048]
    const float* bc  = (const float*)d_in[4];   // [2048]
    const float* bu  = (const float*)d_in[5];   // [2048]
    const float* Why = (const float*)d_in[6];   // [2048,1024]
    const float* by  = (const float*)d_in[7];   // [1024]
    float* out = (float*)d_out;                 // ys[512*1024] then h_final[2048]

    float* ws = (float*)d_ws;
    float* XU = ws;                                       // 512*2048 f32
    float* XC = ws + (T_STEPS * H_DIM);                   // 512*2048 f32
    float* H  = ws + 2 * (T_STEPS * H_DIM);               // 512*2048 f32 (plain)
    unsigned long long* Hx =
        (unsigned long long*)(ws + 3 * (T_STEPS * H_DIM)); // 512*2048 x 8B tagged

    // K1: XU = x @ Wu[0:1024,:] + bu ; XC = x @ Wc[0:1024,:] + bc
    gemm_bias<<<dim3(H_DIM / TN, T_STEPS / TM), 256, 0, stream>>>(
        x, Wu, bu, XU, T_STEPS, H_DIM, IN_DIM, IN_DIM, H_DIM, H_DIM);
    gemm_bias<<<dim3(H_DIM / TN, T_STEPS / TM), 256, 0, stream>>>(
        x, Wc, bc, XC, T_STEPS, H_DIM, IN_DIM, IN_DIM, H_DIM, H_DIM);

    // K2: barrier-free dataflow recurrence
    gru_seq<<<NBLK2, BT2, 0, stream>>>(
        Wu + IN_DIM * H_DIM, Wc + IN_DIM * H_DIM, XU, XC, h0, Hx, H);

    // K3: ys = H @ Why + by
    gemm_bias<<<dim3(Y_DIM / TN, T_STEPS / TM), 256, 0, stream>>>(
        H, Why, by, out, T_STEPS, Y_DIM, H_DIM, H_DIM, Y_DIM, Y_DIM);

    // h_final = H[511]
    hipMemcpyAsync(out + T_STEPS * Y_DIM, H + (T_STEPS - 1) * H_DIM,
                   H_DIM * sizeof(float), hipMemcpyDeviceToDevice, stream);
}

// Round 6
// 2269.566 us; speedup vs baseline: 2.8625x; 2.8625x over previous
//
#include <hip/hip_runtime.h>
#include <hip/hip_bf16.h>
#include <math.h>

// Problem dims (fixed)
#define T_STEPS 512
#define IN_DIM  1024
#define H_DIM   2048
#define Y_DIM   1024

// K2 geometry: 256 blocks x 512 threads (8 waves). Block owns 8 columns,
// wave w owns column jb+w. 82 KB LDS forces exactly 1 block/CU.
#define NBLK2 256
#define BT2   512

// ---------- helpers ----------
static __device__ __forceinline__ unsigned f2bf(float f) {
    unsigned u = __float_as_uint(f);
    return ((u + 0x7FFFu + ((u >> 16) & 1u)) >> 16) & 0xFFFFu;   // RNE
}
static __device__ __forceinline__ float bflo(unsigned p) { return __uint_as_float(p << 16); }
static __device__ __forceinline__ float bfhi(unsigned p) { return __uint_as_float(p & 0xFFFF0000u); }

// ---------- K1 / K3: tiled fp32 GEMM, C[M,N] = A[M,K] @ B[K,N] + bias[N] ----------
#define TM 64
#define TN 128
#define TK 16

__global__ __launch_bounds__(256) void gemm_bias(
    const float* __restrict__ A, const float* __restrict__ B,
    const float* __restrict__ bias, float* __restrict__ C,
    int M, int N, int K, int lda, int ldb, int ldc)
{
    __shared__ float As[TK][TM + 4];
    __shared__ float Bs[TK][TN + 4];

    const int n0 = blockIdx.x * TN;
    const int m0 = blockIdx.y * TM;
    const int tid = threadIdx.x;
    const int tx = tid & 15;        // N: 8 floats each
    const int ty = tid >> 4;        // M: 4 rows each

    float acc[4][8] = {};

    for (int k0 = 0; k0 < K; k0 += TK) {
        {
            int mm = tid & 63, kq = tid >> 6;
            float4 a = *(const float4*)&A[(m0 + mm) * lda + k0 + 4 * kq];
            As[4 * kq + 0][mm] = a.x;
            As[4 * kq + 1][mm] = a.y;
            As[4 * kq + 2][mm] = a.z;
            As[4 * kq + 3][mm] = a.w;
        }
        #pragma unroll
        for (int l = tid; l < 512; l += 256) {
            int kk = l >> 5, jj = (l & 31) * 4;
            *(float4*)&Bs[kk][jj] = *(const float4*)&B[(k0 + kk) * ldb + n0 + jj];
        }
        __syncthreads();
        #pragma unroll
        for (int kk = 0; kk < TK; ++kk) {
            float4 a  = *(const float4*)&As[kk][ty * 4];
            float4 b0 = *(const float4*)&Bs[kk][tx * 8];
            float4 b1 = *(const float4*)&Bs[kk][tx * 8 + 4];
            const float av[4] = {a.x, a.y, a.z, a.w};
            const float bv[8] = {b0.x, b0.y, b0.z, b0.w, b1.x, b1.y, b1.z, b1.w};
            #pragma unroll
            for (int r = 0; r < 4; ++r)
                #pragma unroll
                for (int c = 0; c < 8; ++c)
                    acc[r][c] = fmaf(av[r], bv[c], acc[r][c]);
        }
        __syncthreads();
    }

    float4 bv0 = *(const float4*)&bias[n0 + tx * 8];
    float4 bv1 = *(const float4*)&bias[n0 + tx * 8 + 4];
    const float bb[8] = {bv0.x, bv0.y, bv0.z, bv0.w, bv1.x, bv1.y, bv1.z, bv1.w};
    #pragma unroll
    for (int r = 0; r < 4; ++r) {
        float4 o0, o1;
        o0.x = acc[r][0] + bb[0]; o0.y = acc[r][1] + bb[1];
        o0.z = acc[r][2] + bb[2]; o0.w = acc[r][3] + bb[3];
        o1.x = acc[r][4] + bb[4]; o1.y = acc[r][5] + bb[5];
        o1.z = acc[r][6] + bb[6]; o1.w = acc[r][7] + bb[7];
        float* cp = &C[(m0 + ty * 4 + r) * ldc + n0 + tx * 8];
        *(float4*)cp = o0;
        *(float4*)(cp + 4) = o1;
    }
}

// ---------- K2: barrier-free dataflow recurrence, block-shared h via LDS ----------
// Key change vs R5: h[t-1] is pulled through the coherence point ONCE PER BLOCK
// (each of 8 waves acquires a 256-element slice of tagged pairs, throttled
// retry, writes values to LDS), then all 8 waves compute from LDS.
// IC read traffic: 4 MB/step (was 16 MB/step in R3, 16+ in R5).
// No device-wide barrier at all; one __syncthreads per step (fill -> compute);
// LDS h is double-buffered so no trailing barrier is needed.
__global__ __launch_bounds__(BT2) void gru_seq(
    const float* __restrict__ Wu_h,   // = Wu + IN_DIM*H_DIM  (h-part rows)
    const float* __restrict__ Wc_h,
    const float* __restrict__ XU,     // [T,H]  x@Wu_x + bu
    const float* __restrict__ XC,     // [T,H]  x@Wc_x + bc
    const float* __restrict__ h0,     // [H]
    unsigned long long* __restrict__ Hx,  // [T,H] tagged (f32,epoch) pairs
    float* __restrict__ H)                // [T,H] plain f32 (for K3)
{
    __shared__ unsigned long long lds_w[8 * 1024];  // 64 KB: [w][p] = {wu_pair, wc_pair}
    __shared__ float hbuf[2][2560];                 // 20 KB: double-buffered h (padded
                                                    // so total LDS 84 KB => 1 block/CU)

    const int tid  = threadIdx.x;
    const int w    = tid >> 6;
    const int lane = tid & 63;
    const int jb   = blockIdx.x * 8;
    const int j    = jb + w;

    // ---- one-time weight staging: interleaved {wu,wc} bf16-pair per p ----
    // consecutive tid -> consecutive column (8 cols = 32B span) for some coalescing
    for (int idx = tid; idx < 8192; idx += BT2) {
        int ww = idx & 7, p = idx >> 3;
        int jj = jb + ww;
        float u0 = Wu_h[(size_t)(2 * p) * H_DIM + jj];
        float u1 = Wu_h[(size_t)(2 * p + 1) * H_DIM + jj];
        float c0 = Wc_h[(size_t)(2 * p) * H_DIM + jj];
        float c1 = Wc_h[(size_t)(2 * p + 1) * H_DIM + jj];
        unsigned wu = f2bf(u0) | (f2bf(u1) << 16);
        unsigned wc = f2bf(c0) | (f2bf(c1) << 16);
        lds_w[ww * 1024 + p] = (unsigned long long)wu | ((unsigned long long)wc << 32);
    }

    float hc = h0[j];                 // carried own h value (lane0's copy is used)
    const int e0 = w * 256 + lane;    // this wave's acquire-slice base element

    __syncthreads();                  // weights staged

    for (int t = 0; t < T_STEPS; ++t) {
        // x-contributions (normal cached loads, independent of acquire)
        float xu = 0.f, xc = 0.f;
        if (lane == 0) {
            xu = XU[(size_t)t * H_DIM + j];
            xc = XC[(size_t)t * H_DIM + j];
        }

        float* hb = hbuf[t & 1];

        // ---- acquire this wave's 256-element slice of h[t-1] into LDS ----
        if (t == 0) {
            #pragma unroll
            for (int i = 0; i < 4; ++i)
                hb[e0 + i * 64] = h0[e0 + i * 64];
        } else {
            const unsigned long long* src = Hx + (size_t)(t - 1) * H_DIM;
            unsigned long long p0, p1, p2, p3;
            p0 = __hip_atomic_load(src + e0,       __ATOMIC_RELAXED, __HIP_MEMORY_SCOPE_AGENT);
            p1 = __hip_atomic_load(src + e0 + 64,  __ATOMIC_RELAXED, __HIP_MEMORY_SCOPE_AGENT);
            p2 = __hip_atomic_load(src + e0 + 128, __ATOMIC_RELAXED, __HIP_MEMORY_SCOPE_AGENT);
            p3 = __hip_atomic_load(src + e0 + 192, __ATOMIC_RELAXED, __HIP_MEMORY_SCOPE_AGENT);
            const unsigned tag = (unsigned)t;
            unsigned stale = 0;
            if ((unsigned)(p0 >> 32) != tag) stale |= 1u;
            if ((unsigned)(p1 >> 32) != tag) stale |= 2u;
            if ((unsigned)(p2 >> 32) != tag) stale |= 4u;
            if ((unsigned)(p3 >> 32) != tag) stale |= 8u;
            while (__any(stale != 0u)) {
                __builtin_amdgcn_s_sleep(1);   // throttle: ~64cy between retry rounds
                if (stale & 1u) {
                    p0 = __hip_atomic_load(src + e0,       __ATOMIC_RELAXED, __HIP_MEMORY_SCOPE_AGENT);
                    if ((unsigned)(p0 >> 32) == tag) stale &= ~1u;
                }
                if (stale & 2u) {
                    p1 = __hip_atomic_load(src + e0 + 64,  __ATOMIC_RELAXED, __HIP_MEMORY_SCOPE_AGENT);
                    if ((unsigned)(p1 >> 32) == tag) stale &= ~2u;
                }
                if (stale & 4u) {
                    p2 = __hip_atomic_load(src + e0 + 128, __ATOMIC_RELAXED, __HIP_MEMORY_SCOPE_AGENT);
                    if ((unsigned)(p2 >> 32) == tag) stale &= ~4u;
                }
                if (stale & 8u) {
                    p3 = __hip_atomic_load(src + e0 + 192, __ATOMIC_RELAXED, __HIP_MEMORY_SCOPE_AGENT);
                    if ((unsigned)(p3 >> 32) == tag) stale &= ~8u;
                }
            }
            hb[e0]       = __uint_as_float((unsigned)p0);
            hb[e0 + 64]  = __uint_as_float((unsigned)p1);
            hb[e0 + 128] = __uint_as_float((unsigned)p2);
            hb[e0 + 192] = __uint_as_float((unsigned)p3);
        }
        __syncthreads();   // h[t-1] fully in LDS

        // ---- dot products from LDS (2 x ds_read_b64 + 4 FMA per q) ----
        float au = 0.f, ac = 0.f;
        const unsigned long long* wrow = lds_w + w * 1024;
        #pragma unroll
        for (int q = 0; q < 16; ++q) {
            int p = q * 64 + lane;
            float2 h2 = *(const float2*)&hb[2 * p];
            uint2  wp = *(const uint2*)&wrow[p];
            au = fmaf(h2.x, bflo(wp.x), au);
            au = fmaf(h2.y, bfhi(wp.x), au);
            ac = fmaf(h2.x, bflo(wp.y), ac);
            ac = fmaf(h2.y, bfhi(wp.y), ac);
        }
        #pragma unroll
        for (int off = 32; off; off >>= 1) {
            au += __shfl_down(au, off);
            ac += __shfl_down(ac, off);
        }

        if (lane == 0) {
            float ug = 1.f / (1.f + expf(-(au + xu)));
            float cg = tanhf(ac + xc);
            float hn = ug * cg + (1.f - ug) * hc;
            hc = hn;
            // tagged publish (value+epoch travel atomically; no fence needed)
            __hip_atomic_store(Hx + (size_t)t * H_DIM + j,
                               ((unsigned long long)(unsigned)(t + 1) << 32) |
                                   __float_as_uint(hn),
                               __ATOMIC_RELAXED, __HIP_MEMORY_SCOPE_AGENT);
            // plain copy for K3 (kernel-boundary flush makes it visible)
            H[(size_t)t * H_DIM + j] = hn;
        }
        // no trailing barrier: hbuf is double-buffered, and a wave can only be
        // 1 step ahead of its block-mates (it needs their Hx[t] to pass acquire)
    }
}

extern "C" void kernel_launch(void* const* d_in, const int* in_sizes, int n_in,
                              void* d_out, int out_size, void* d_ws, size_t ws_size,
                              hipStream_t stream)
{
    const float* x   = (const float*)d_in[0];   // [1,512,1024]
    const float* h0  = (const float*)d_in[1];   // [2048]
    const float* Wc  = (const float*)d_in[2];   // [3072,2048]
    const float* Wu  = (const float*)d_in[3];   // [3072,2048]
    const float* bc  = (const float*)d_in[4];   // [2048]
    const float* bu  = (const float*)d_in[5];   // [2048]
    const float* Why = (const float*)d_in[6];   // [2048,1024]
    const float* by  = (const float*)d_in[7];   // [1024]
    float* out = (float*)d_out;                 // ys[512*1024] then h_final[2048]

    float* ws = (float*)d_ws;
    float* XU = ws;                                        // 512*2048 f32
    float* XC = ws + (T_STEPS * H_DIM);                    // 512*2048 f32
    float* H  = ws + 2 * (T_STEPS * H_DIM);                // 512*2048 f32 (plain)
    unsigned long long* Hx =
        (unsigned long long*)(ws + 3 * (T_STEPS * H_DIM)); // 512*2048 tagged 8B

    // K1: XU = x @ Wu[0:1024,:] + bu ; XC = x @ Wc[0:1024,:] + bc
    gemm_bias<<<dim3(H_DIM / TN, T_STEPS / TM), 256, 0, stream>>>(
        x, Wu, bu, XU, T_STEPS, H_DIM, IN_DIM, IN_DIM, H_DIM, H_DIM);
    gemm_bias<<<dim3(H_DIM / TN, T_STEPS / TM), 256, 0, stream>>>(
        x, Wc, bc, XC, T_STEPS, H_DIM, IN_DIM, IN_DIM, H_DIM, H_DIM);

    // K2: barrier-free dataflow recurrence (Hx needs no init: 0xAA poison
    // can never equal a valid epoch 1..512)
    gru_seq<<<NBLK2, BT2, 0, stream>>>(
        Wu + IN_DIM * H_DIM, Wc + IN_DIM * H_DIM, XU, XC, h0, Hx, H);

    // K3: ys = H @ Why + by
    gemm_bias<<<dim3(Y_DIM / TN, T_STEPS / TM), 256, 0, stream>>>(
        H, Why, by, out, T_STEPS, Y_DIM, H_DIM, H_DIM, Y_DIM, Y_DIM);

    // h_final = H[511]
    hipMemcpyAsync(out + T_STEPS * Y_DIM, H + (T_STEPS - 1) * H_DIM,
                   H_DIM * sizeof(float), hipMemcpyDeviceToDevice, stream);
}